// Round 1
// baseline (90.954 us; speedup 1.0000x reference)
//
#include <hip/hip_runtime.h>

// PGA G(3,0,1) geometric product, pairwise: out[n,m,:] = T[n] * reverse(T[m]).
// Structure constants generated at compile time (constexpr), mirroring the
// reference's bubble-sort + metric-contraction construction.

namespace {

constexpr int popcount4(unsigned x) {
    int c = 0;
    for (int i = 0; i < 5; ++i) c += (x >> i) & 1;
    return c;
}

struct GPTab {
    signed char sgn[16][16];   // sign of e_j * e_k (rev[k] folded in); 0 if product vanishes
    unsigned char idx[16][16]; // output blade index of e_j * e_k
};

constexpr GPTab make_tab() {
    GPTab t{};
    // Blade bitmasks in the reference's basis order:
    // (), e0..e3, e01,e02,e03,e12,e13,e23, e012,e013,e023,e123, e0123
    unsigned MASK[16] = {0u, 1u, 2u, 4u, 8u,
                         3u, 5u, 9u, 6u, 10u, 12u,
                         7u, 11u, 13u, 14u, 15u};
    int inv[16] = {};
    for (int i = 0; i < 16; ++i) inv[(int)MASK[i]] = i;

    for (int j = 0; j < 16; ++j) {
        for (int k = 0; k < 16; ++k) {
            unsigned a = MASK[j], b = MASK[k];
            if (a & b & 1u) {            // shared e0 -> e0^2 = 0
                t.sgn[j][k] = 0;
                t.idx[j][k] = 0;
                continue;
            }
            // sign from anticommuting each generator g of b past generators of a
            // that are greater than g
            int swaps = 0;
            for (int g = 0; g < 4; ++g)
                if ((b >> g) & 1u)
                    swaps += popcount4(a >> (g + 1));
            int s = (swaps & 1) ? -1 : 1;
            // fold reverse(v) sign on the k (second) operand: (-1)^{r(r-1)/2}
            int r = popcount4(b);
            if ((r * (r - 1) / 2) & 1) s = -s;
            t.sgn[j][k] = (signed char)s;
            t.idx[j][k] = (unsigned char)inv[(int)(a ^ b)];
        }
    }
    return t;
}

constexpr GPTab TAB = make_tab();

} // namespace

__global__ __launch_bounds__(256) void gp_pairs_kernel(
    const float* __restrict__ T, float* __restrict__ out, unsigned nrows) {
    const unsigned tid = blockIdx.x * 256u + threadIdx.x;
    const unsigned n = tid / nrows;
    const unsigned m = tid - n * nrows;

    const float4* __restrict__ Tv = reinterpret_cast<const float4*>(T);

    float a[16], b[16];
#pragma unroll
    for (int q = 0; q < 4; ++q) {
        float4 va = Tv[(size_t)n * 4 + q];
        a[q * 4 + 0] = va.x; a[q * 4 + 1] = va.y;
        a[q * 4 + 2] = va.z; a[q * 4 + 3] = va.w;
        float4 vb = Tv[(size_t)m * 4 + q];
        b[q * 4 + 0] = vb.x; b[q * 4 + 1] = vb.y;
        b[q * 4 + 2] = vb.z; b[q * 4 + 3] = vb.w;
    }

    float o[16];
#pragma unroll
    for (int i = 0; i < 16; ++i) o[i] = 0.0f;

#pragma unroll
    for (int j = 0; j < 16; ++j) {
#pragma unroll
        for (int k = 0; k < 16; ++k) {
            const int s = TAB.sgn[j][k];   // compile-time constant after unroll
            const int i = TAB.idx[j][k];
            if (s == 1) {
                o[i] = fmaf(a[j], b[k], o[i]);
            } else if (s == -1) {
                o[i] = fmaf(-a[j], b[k], o[i]);
            }
        }
    }

    float4* __restrict__ ov = reinterpret_cast<float4*>(out) + (size_t)tid * 4;
#pragma unroll
    for (int q = 0; q < 4; ++q) {
        ov[q] = make_float4(o[q * 4 + 0], o[q * 4 + 1], o[q * 4 + 2], o[q * 4 + 3]);
    }
}

extern "C" void kernel_launch(void* const* d_in, const int* in_sizes, int n_in,
                              void* d_out, int out_size, void* d_ws, size_t ws_size,
                              hipStream_t stream) {
    const float* T = (const float*)d_in[0];
    float* out = (float*)d_out;
    const unsigned nrows = (unsigned)(in_sizes[0] / 16);   // 2048
    const size_t total = (size_t)nrows * nrows;            // one thread per (n,m)
    const unsigned block = 256;
    const unsigned grid = (unsigned)((total + block - 1) / block);
    gp_pairs_kernel<<<grid, block, 0, stream>>>(T, out, nrows);
}

// Round 2
// 50.017 us; speedup vs baseline: 1.8185x; 1.8185x over previous
//
#include <hip/hip_runtime.h>

// PGA G(3,0,1) geometric product, pairwise: out[n,m,:] = T[n] * reverse(T[m]).
// R1: fix request amplification. Stores go through an LDS transpose so each
// global_store_dwordx4 is lane-contiguous (1 KB/instr). b-operand loads read a
// pre-transposed copy of T (component-major) so they are fully coalesced.

namespace {

constexpr int popcount4(unsigned x) {
    int c = 0;
    for (int i = 0; i < 5; ++i) c += (x >> i) & 1;
    return c;
}

struct GPTab {
    signed char sgn[16][16];   // sign of e_j * e_k (rev on k folded in); 0 if vanishes
    unsigned char idx[16][16]; // output blade index of e_j * e_k
};

constexpr GPTab make_tab() {
    GPTab t{};
    // Blade bitmasks in the reference's basis order:
    // (), e0..e3, e01,e02,e03,e12,e13,e23, e012,e013,e023,e123, e0123
    unsigned MASK[16] = {0u, 1u, 2u, 4u, 8u,
                         3u, 5u, 9u, 6u, 10u, 12u,
                         7u, 11u, 13u, 14u, 15u};
    int inv[16] = {};
    for (int i = 0; i < 16; ++i) inv[(int)MASK[i]] = i;

    for (int j = 0; j < 16; ++j) {
        for (int k = 0; k < 16; ++k) {
            unsigned a = MASK[j], b = MASK[k];
            if (a & b & 1u) {            // shared e0 -> e0^2 = 0
                t.sgn[j][k] = 0;
                t.idx[j][k] = 0;
                continue;
            }
            int swaps = 0;
            for (int g = 0; g < 4; ++g)
                if ((b >> g) & 1u)
                    swaps += popcount4(a >> (g + 1));
            int s = (swaps & 1) ? -1 : 1;
            int r = popcount4(b);
            if ((r * (r - 1) / 2) & 1) s = -s;   // reverse() sign on 2nd operand
            t.sgn[j][k] = (signed char)s;
            t.idx[j][k] = (unsigned char)inv[(int)(a ^ b)];
        }
    }
    return t;
}

constexpr GPTab TAB = make_tab();

} // namespace

// Tt[j*nrows + m] = T[m*16 + j]   (component-major copy, 128 KB)
__global__ __launch_bounds__(256) void transpose_kernel(
    const float* __restrict__ T, float* __restrict__ Tt, int nrows) {
    int t = blockIdx.x * 256 + threadIdx.x;
    if (t < nrows * 16) {
        int m = t >> 4, j = t & 15;
        Tt[j * nrows + m] = T[t];
    }
}

template <bool USE_TT>
__global__ __launch_bounds__(256) void gp_pairs_kernel(
    const float* __restrict__ T, const float* __restrict__ Tt,
    float* __restrict__ out, int nrows) {
    const int lane = threadIdx.x & 63;
    const int wave = threadIdx.x >> 6;
    const int m = blockIdx.x * 256 + (int)threadIdx.x;
    const int n = blockIdx.y;                 // wave-uniform
    const int mc = (m < nrows) ? m : (nrows - 1);  // clamp for safety

    // 64 pairs/wave, 20-float padded stride (80 B, 16B-aligned) per pair.
    __shared__ float lds[4][64 * 20];

    float a[16], b[16];
#pragma unroll
    for (int q = 0; q < 4; ++q) {             // uniform address -> broadcast/scalar
        float4 va = reinterpret_cast<const float4*>(T)[(size_t)n * 4 + q];
        a[q * 4 + 0] = va.x; a[q * 4 + 1] = va.y;
        a[q * 4 + 2] = va.z; a[q * 4 + 3] = va.w;
    }
    if constexpr (USE_TT) {
#pragma unroll
        for (int j = 0; j < 16; ++j)          // fully coalesced: lane i -> +4B
            b[j] = Tt[(size_t)j * nrows + mc];
    } else {
#pragma unroll
        for (int q = 0; q < 4; ++q) {
            float4 vb = reinterpret_cast<const float4*>(T)[(size_t)mc * 4 + q];
            b[q * 4 + 0] = vb.x; b[q * 4 + 1] = vb.y;
            b[q * 4 + 2] = vb.z; b[q * 4 + 3] = vb.w;
        }
    }

    float o[16];
#pragma unroll
    for (int i = 0; i < 16; ++i) o[i] = 0.0f;

#pragma unroll
    for (int j = 0; j < 16; ++j) {
#pragma unroll
        for (int k = 0; k < 16; ++k) {
            const int s = TAB.sgn[j][k];      // compile-time constants after unroll
            const int i = TAB.idx[j][k];
            if (s == 1) {
                o[i] = fmaf(a[j], b[k], o[i]);
            } else if (s == -1) {
                o[i] = fmaf(-a[j], b[k], o[i]);
            }
        }
    }

    // Stage this wave's 64x16 output tile in LDS (padded), then store coalesced.
    float* w = &lds[wave][lane * 20];
#pragma unroll
    for (int q = 0; q < 4; ++q)
        *reinterpret_cast<float4*>(w + q * 4) =
            make_float4(o[q * 4 + 0], o[q * 4 + 1], o[q * 4 + 2], o[q * 4 + 3]);

    __syncthreads();

    const int waveM0 = blockIdx.x * 256 + wave * 64;
    float4* __restrict__ ov =
        reinterpret_cast<float4*>(out) + ((size_t)n * nrows + waveM0) * 4;
#pragma unroll
    for (int q = 0; q < 4; ++q) {
        const int g = q * 64 + lane;          // float4 index within wave tile
        const int p = g >> 2;                 // pair within wave
        const int c = g & 3;                  // float4 chunk within pair
        if (waveM0 + p < nrows) {
            ov[g] = *reinterpret_cast<const float4*>(&lds[wave][p * 20 + c * 4]);
        }
    }
}

extern "C" void kernel_launch(void* const* d_in, const int* in_sizes, int n_in,
                              void* d_out, int out_size, void* d_ws, size_t ws_size,
                              hipStream_t stream) {
    const float* T = (const float*)d_in[0];
    float* out = (float*)d_out;
    const int nrows = in_sizes[0] / 16;       // 2048
    const size_t tt_bytes = (size_t)nrows * 16 * sizeof(float);

    dim3 grid((unsigned)((nrows + 255) / 256), (unsigned)nrows, 1);

    if (ws_size >= tt_bytes) {
        float* Tt = (float*)d_ws;
        transpose_kernel<<<(nrows * 16 + 255) / 256, 256, 0, stream>>>(T, Tt, nrows);
        gp_pairs_kernel<true><<<grid, 256, 0, stream>>>(T, Tt, out, nrows);
    } else {
        gp_pairs_kernel<false><<<grid, 256, 0, stream>>>(T, nullptr, out, nrows);
    }
}